// Round 4
// baseline (334.647 us; speedup 1.0000x reference)
//
#include <hip/hip_runtime.h>
#include <stdint.h>

#define THRESH 0.5f
#define PSI 0.1f

typedef short bfrag_t __attribute__((ext_vector_type(8)));     // 8 bf16 = 4 VGPRs (MFMA A/B frag)
typedef float f32x16 __attribute__((ext_vector_type(16)));     // 32x32 MFMA C/D frag
typedef unsigned short u16x8 __attribute__((ext_vector_type(8)));

// async global->LDS, 16B per lane, wave-uniform LDS base + lane*16
#define GLD16(gsrc, ldst)                                                                \
    __builtin_amdgcn_global_load_lds((const __attribute__((address_space(1))) void*)(gsrc), \
                                     (__attribute__((address_space(3))) void*)(ldst),       \
                                     16, 0, 0)

#define WAITVM(n) asm volatile("s_waitcnt vmcnt(" #n ")" ::: "memory")
#define BAR()                                  \
    do {                                       \
        asm volatile("" ::: "memory");         \
        __builtin_amdgcn_s_barrier();          \
        asm volatile("" ::: "memory");         \
    } while (0)

__device__ __forceinline__ float dequant(float v) {
    if (v > THRESH) return 1.0f;
    if (v < -THRESH) return -1.0f;
    if (fabsf(v) < PSI) return 0.0f;
    return (v + THRESH) / (2.0f * THRESH);
}

__device__ __forceinline__ unsigned short f2bf(float f) {
    unsigned int u = __float_as_uint(f);
    u += 0x7FFFu + ((u >> 16) & 1u);
    return (unsigned short)(u >> 16);
}

__global__ void quantW_kernel(const float* __restrict__ w, unsigned short* __restrict__ wb, int n8) {
    const int stride = gridDim.x * blockDim.x;
    for (int i = blockIdx.x * blockDim.x + threadIdx.x; i < n8; i += stride) {
        const float4* p = (const float4*)w + (size_t)i * 2;
        float4 a = p[0], b = p[1];
        u16x8 o;
        o[0] = f2bf(dequant(a.x)); o[1] = f2bf(dequant(a.y));
        o[2] = f2bf(dequant(a.z)); o[3] = f2bf(dequant(a.w));
        o[4] = f2bf(dequant(b.x)); o[5] = f2bf(dequant(b.y));
        o[6] = f2bf(dequant(b.z)); o[7] = f2bf(dequant(b.w));
        *(u16x8*)(wb + (size_t)i * 8) = o;
    }
}

__global__ void cvtX_kernel(const float* __restrict__ x, unsigned short* __restrict__ xb, int n8) {
    const int stride = gridDim.x * blockDim.x;
    for (int i = blockIdx.x * blockDim.x + threadIdx.x; i < n8; i += stride) {
        const float4* p = (const float4*)x + (size_t)i * 2;
        float4 a = p[0], b = p[1];
        u16x8 o;
        o[0] = f2bf(a.x); o[1] = f2bf(a.y); o[2] = f2bf(a.z); o[3] = f2bf(a.w);
        o[4] = f2bf(b.x); o[5] = f2bf(b.y); o[6] = f2bf(b.z); o[7] = f2bf(b.w);
        *(u16x8*)(xb + (size_t)i * 8) = o;
    }
}

// ---------------------------------------------------------------------------
// 256x256 8-phase bf16 GEMM with 32x32x16 MFMA.
// C[M,N] = A[M,K] * B[N,K]^T + bias, fp32 out.
// 8 waves (2Mx4N), per-wave 128x64 = 4x2 frags of 32x32.
// LDS half-tile layout (16 KiB, logical [256 rows][32 k] bf16), banded:
//   addr = (row>>5)*2048 + ks*1024 + ((k>>3)&1)*512 + (row&31)*16 + (k&7)*2
// i.e. band(row) -> ks(k/16) -> lane-linear granules. A fragment read at
// 32-aligned base row, fixed ks, is then base + lane*16: conflict-free.
// Writes (global_load_lds) are linear; the global SOURCE address absorbs
// the permutation. BK=64 as two 32-k halves, 128 KiB LDS double-buffered,
// counted vmcnt(8), raw s_barrier, setprio, XCD-swizzled blockIdx.
// ---------------------------------------------------------------------------

// read one 32x32x16 A/B fragment: lane l -> row R0+(l&31), k = ks*16+(l>>5)*8..+7
// addr = halfBase + (R0>>5)*2048 + ks*1024 + l*16   (linear in lane!)
__device__ __forceinline__ bfrag_t rdfrag32(const char* halfBase, int band, int ks, int l16) {
    return *(const bfrag_t*)(halfBase + (band << 11) + (ks << 10) + l16);
}

__device__ __forceinline__ void mfma_half(f32x16 (&acc)[4][2], int mbase,
                                          const bfrag_t (&a)[2][2], const bfrag_t (&b)[2][2]) {
#pragma unroll
    for (int ks = 0; ks < 2; ++ks)
#pragma unroll
        for (int mi = 0; mi < 2; ++mi)
#pragma unroll
            for (int nn = 0; nn < 2; ++nn)
                acc[mbase + mi][nn] = __builtin_amdgcn_mfma_f32_32x32x16_bf16(
                    a[mi][ks], b[nn][ks], acc[mbase + mi][nn], 0, 0, 0);
}

__global__ __launch_bounds__(512, 2) void gemm256_kernel(
        const unsigned short* __restrict__ A,   // M x K, bf16 bits
        const unsigned short* __restrict__ B,   // N x K, bf16 bits
        const float* __restrict__ bias,         // N
        float* __restrict__ C,                  // M x N
        int M, int N, int K) {
    __shared__ unsigned short lds[65536];       // 128 KiB: 2 bufs x {A0,A1,B0,B1} x 16 KiB
    char* ldsB = (char*)lds;

    const int t    = threadIdx.x;
    const int w    = t >> 6;        // wave 0..7
    const int l    = t & 63;
    const int wr   = w >> 2;        // 0..1  (128-row band)
    const int wc   = w & 3;         // 0..3  (64-col band)
    const int lr32 = l & 31;
    const int hi   = l >> 5;
    const int l16  = l << 4;

    // XCD-aware block swizzle (bijective when nwg % 8 == 0)
    const int nwg = gridDim.x;
    int bid = blockIdx.x;
    if ((nwg & 7) == 0) bid = (bid & 7) * (nwg >> 3) + (bid >> 3);
    const int nbn  = N >> 8;
    const int brow = (bid / nbn) << 8;
    const int bcol = (bid % nbn) << 8;

    // staging source coords: thread covers LDS 16B granules of chunks c16 = w*2+{0,1}.
    // LDS byte b = c16*1024 + l*16  ->  band = c16>>1, ks = c16&1, row = band*32+(l&31),
    // k element = ks*16 + (l>>5)*8.
    const int c16a = w * 2 + 0, c16b = w * 2 + 1;
    const int rowA = ((c16a >> 1) << 5) + lr32;
    const int rowB = ((c16b >> 1) << 5) + lr32;    // same band as rowA (c16b>>1 == c16a>>1)
    const int kelA = ((c16a & 1) << 4) + (hi << 3);
    const int kelB = ((c16b & 1) << 4) + (hi << 3);

    const unsigned short* aS0 = A + (size_t)(brow + rowA) * K + kelA;
    const unsigned short* aS1 = A + (size_t)(brow + rowB) * K + kelB;
    const unsigned short* bS0 = B + (size_t)(bcol + rowA) * K + kelA;
    const unsigned short* bS1 = B + (size_t)(bcol + rowB) * K + kelB;

    // LDS half-tile bases (bytes): buf*65536 + {A0:0, A1:16384, B0:32768, B1:49152}
#define STAGE_A(buf, half, kE)                                                              \
    do {                                                                                    \
        GLD16(aS0 + (kE) + (half) * 32, ldsB + (buf) * 65536 + (half) * 16384 + c16a * 1024); \
        GLD16(aS1 + (kE) + (half) * 32, ldsB + (buf) * 65536 + (half) * 16384 + c16b * 1024); \
    } while (0)
#define STAGE_B(buf, half, kE)                                                              \
    do {                                                                                    \
        GLD16(bS0 + (kE) + (half) * 32, ldsB + (buf) * 65536 + 32768 + (half) * 16384 + c16a * 1024); \
        GLD16(bS1 + (kE) + (half) * 32, ldsB + (buf) * 65536 + 32768 + (half) * 16384 + c16b * 1024); \
    } while (0)

    f32x16 acc[4][2];
#pragma unroll
    for (int m = 0; m < 4; ++m)
#pragma unroll
        for (int n = 0; n < 2; ++n)
#pragma unroll
            for (int r = 0; r < 16; ++r)
                acc[m][n][r] = 0.f;

    const int NT = K >> 6;
    const int wrB4 = wr << 2;       // A band base: wr*4 (+mi, +2+mi)
    const int wcB2 = wc << 1;       // B band base: wc*2 (+nn)
    const int wrBase = wr << 7;
    const int wcBase = wc << 6;

    // ---- prologue: buf0 fully (A0,B0,A1,B1), buf1 (A0,B0) ----
    {
        const int k1 = (NT > 1) ? 64 : 0;
        STAGE_A(0, 0, 0); STAGE_B(0, 0, 0);
        STAGE_A(0, 1, 0); STAGE_B(0, 1, 0);
        STAGE_A(1, 0, k1); STAGE_B(1, 0, k1);
        WAITVM(4);          // buf0 complete; buf1.A0/B0 (4 issues) stay in flight
        BAR();
    }

    for (int tt = 0; tt < NT; ++tt) {
        const int X = tt & 1, Y = X ^ 1;
        const char* aH0 = ldsB + X * 65536;
        const char* aH1 = aH0 + 16384;
        const char* bH0 = aH0 + 32768;
        const char* bH1 = aH0 + 49152;
        int t1 = tt + 1; if (t1 >= NT) t1 -= NT;   // wrapped: data harmless, never read
        int t2 = tt + 2; if (t2 >= NT) t2 -= NT;
        const int kY1 = t1 << 6;
        const int kX2 = t2 << 6;

        bfrag_t a[2][2], b[2][2];

        // ---- phase 1: A m0-1 + B all (k-half 0); stage Y.A1(t+1); 8 MFMA ----
#pragma unroll
        for (int mi = 0; mi < 2; ++mi)
#pragma unroll
            for (int ks = 0; ks < 2; ++ks)
                a[mi][ks] = rdfrag32(aH0, wrB4 + mi, ks, l16);
#pragma unroll
        for (int nn = 0; nn < 2; ++nn)
#pragma unroll
            for (int ks = 0; ks < 2; ++ks)
                b[nn][ks] = rdfrag32(bH0, wcB2 + nn, ks, l16);
        STAGE_A(Y, 1, kY1);
        BAR();
        __builtin_amdgcn_s_setprio(1);
        mfma_half(acc, 0, a, b);
        __builtin_amdgcn_s_setprio(0);
        BAR();

        // ---- phase 2: A m2-3 (k-half 0); stage Y.B1(t+1); 8 MFMA ----
#pragma unroll
        for (int mi = 0; mi < 2; ++mi)
#pragma unroll
            for (int ks = 0; ks < 2; ++ks)
                a[mi][ks] = rdfrag32(aH0, wrB4 + 2 + mi, ks, l16);
        STAGE_B(Y, 1, kY1);
        BAR();
        __builtin_amdgcn_s_setprio(1);
        mfma_half(acc, 2, a, b);
        __builtin_amdgcn_s_setprio(0);
        WAITVM(8);          // completes buf(t).A1/B1 for phase 3
        BAR();

        // ---- phase 3: A m0-1 + B all (k-half 1); stage X.A0(t+2); 8 MFMA ----
#pragma unroll
        for (int mi = 0; mi < 2; ++mi)
#pragma unroll
            for (int ks = 0; ks < 2; ++ks)
                a[mi][ks] = rdfrag32(aH1, wrB4 + mi, ks, l16);
#pragma unroll
        for (int nn = 0; nn < 2; ++nn)
#pragma unroll
            for (int ks = 0; ks < 2; ++ks)
                b[nn][ks] = rdfrag32(bH1, wcB2 + nn, ks, l16);
        STAGE_A(X, 0, kX2);                      // X.A0 free: last read was phase 2
        BAR();
        __builtin_amdgcn_s_setprio(1);
        mfma_half(acc, 0, a, b);
        __builtin_amdgcn_s_setprio(0);
        BAR();

        // ---- phase 4: A m2-3 (k-half 1); stage X.B0(t+2); 8 MFMA ----
#pragma unroll
        for (int mi = 0; mi < 2; ++mi)
#pragma unroll
            for (int ks = 0; ks < 2; ++ks)
                a[mi][ks] = rdfrag32(aH1, wrB4 + 2 + mi, ks, l16);
        STAGE_B(X, 0, kX2);                      // X.B0 free: last read was phase 1
        BAR();
        __builtin_amdgcn_s_setprio(1);
        mfma_half(acc, 2, a, b);
        __builtin_amdgcn_s_setprio(0);
        WAITVM(8);          // completes buf(t+1).A0/B0 for next tile's phase 1
        BAR();
    }

    WAITVM(0);              // drain pending LDS writes before wave retires

    // ---- epilogue: 32x32 C/D layout col=lane&31, row=(reg&3)+8*(reg>>2)+4*(lane>>5) ----
    float bv[2];
#pragma unroll
    for (int nn = 0; nn < 2; ++nn) bv[nn] = bias[bcol + wcBase + nn * 32 + lr32];
#pragma unroll
    for (int mm = 0; mm < 4; ++mm) {
#pragma unroll
        for (int nn = 0; nn < 2; ++nn) {
            const int gc = bcol + wcBase + nn * 32 + lr32;
#pragma unroll
            for (int reg = 0; reg < 16; ++reg) {
                const int row = (reg & 3) + 8 * (reg >> 2) + 4 * hi;
                C[(size_t)(brow + wrBase + mm * 32 + row) * N + gc] = acc[mm][nn][reg] + bv[nn];
            }
        }
    }
    (void)M;
#undef STAGE_A
#undef STAGE_B
}

// ---------------------------------------------------------------------------
// Fallback: fp32 tiled GEMM with on-the-fly dequant (any shape, slow).
// ---------------------------------------------------------------------------
__global__ void gemm_fallback_kernel(const float* __restrict__ X, const float* __restrict__ W,
                                     const float* __restrict__ bias, float* __restrict__ C,
                                     int M, int N, int K) {
    __shared__ float sX[16][17];
    __shared__ float sW[16][17];
    const int tx = threadIdx.x & 15;
    const int ty = threadIdx.x >> 4;
    const int row = blockIdx.y * 16 + ty;
    const int colBase = blockIdx.x * 16;
    const int col = colBase + tx;
    float acc = 0.f;
    for (int k0 = 0; k0 < K; k0 += 16) {
        sX[ty][tx] = (row < M && k0 + tx < K) ? X[(size_t)row * K + k0 + tx] : 0.f;
        const int wrow = colBase + ty;
        sW[ty][tx] = (wrow < N && k0 + tx < K) ? dequant(W[(size_t)wrow * K + k0 + tx]) : 0.f;
        __syncthreads();
#pragma unroll
        for (int kk = 0; kk < 16; ++kk)
            acc += sX[ty][kk] * sW[tx][kk];
        __syncthreads();
    }
    if (row < M && col < N)
        C[(size_t)row * N + col] = acc + bias[col];
}

extern "C" void kernel_launch(void* const* d_in, const int* in_sizes, int n_in,
                              void* d_out, int out_size, void* d_ws, size_t ws_size,
                              hipStream_t stream) {
    const float* x    = (const float*)d_in[0];
    const float* w    = (const float*)d_in[1];
    const float* bias = (const float*)d_in[2];
    float* out        = (float*)d_out;

    const int N = in_sizes[2];
    const int K = in_sizes[1] / N;
    const int M = in_sizes[0] / K;

    const size_t need = ((size_t)M * K + (size_t)N * K) * sizeof(unsigned short);
    const bool fast = (ws_size >= need) && (M % 256 == 0) && (N % 256 == 0) && (K % 64 == 0) && (K >= 128);

    if (fast) {
        unsigned short* xb = (unsigned short*)d_ws;
        unsigned short* wb = xb + (size_t)M * K;
        cvtX_kernel<<<dim3(2048), dim3(256), 0, stream>>>(x, xb, (M * K) / 8);
        quantW_kernel<<<dim3(2048), dim3(256), 0, stream>>>(w, wb, (N * K) / 8);
        gemm256_kernel<<<dim3((M / 256) * (N / 256)), dim3(512), 0, stream>>>(xb, wb, bias, out, M, N, K);
    } else {
        dim3 g((N + 15) / 16, (M + 15) / 16);
        gemm_fallback_kernel<<<g, dim3(256), 0, stream>>>(x, w, bias, out, M, N, K);
    }
    (void)n_in; (void)out_size;
}

// Round 5
// 286.219 us; speedup vs baseline: 1.1692x; 1.1692x over previous
//
#include <hip/hip_runtime.h>
#include <stdint.h>

#define THRESH 0.5f
#define PSI 0.1f

typedef short bfrag_t __attribute__((ext_vector_type(8)));     // 8 bf16 = 4 VGPRs (MFMA A/B frag)
typedef float f32x16 __attribute__((ext_vector_type(16)));     // 32x32 MFMA C/D frag
typedef unsigned short u16x8 __attribute__((ext_vector_type(8)));

// async global->LDS, 16B per lane, wave-uniform LDS base + lane*16
#define GLD16(gsrc, ldst)                                                                \
    __builtin_amdgcn_global_load_lds((const __attribute__((address_space(1))) void*)(gsrc), \
                                     (__attribute__((address_space(3))) void*)(ldst),       \
                                     16, 0, 0)

#define WAITVM(n) asm volatile("s_waitcnt vmcnt(" #n ")" ::: "memory")
#define BAR()                                  \
    do {                                       \
        asm volatile("" ::: "memory");         \
        __builtin_amdgcn_s_barrier();          \
        asm volatile("" ::: "memory");         \
    } while (0)

__device__ __forceinline__ float dequant(float v) {
    if (v > THRESH) return 1.0f;
    if (v < -THRESH) return -1.0f;
    if (fabsf(v) < PSI) return 0.0f;
    return (v + THRESH) / (2.0f * THRESH);
}

__device__ __forceinline__ unsigned short f2bf(float f) {
    unsigned int u = __float_as_uint(f);
    u += 0x7FFFu + ((u >> 16) & 1u);
    return (unsigned short)(u >> 16);
}

// ---------------------------------------------------------------------------
// Packing kernels: convert fp32 row-major [R][K] into bf16 "chunk-linear"
// format matched to the GEMM's LDS layout:
//   granule (r, S, hi) = 8 elems src[r][16S+8hi .. +7]
//   packed element offset = ((r/32)*(K/16) + S)*512 + (hi*32 + (r&32-1))*8
// Block = one 32-row band x 256-k slice (16 chunks = 16KB). LDS bounce keeps
// both global reads (row-major) and writes (packed) fully coalesced.
// ---------------------------------------------------------------------------
template <bool DO_DEQUANT>
__global__ void pack_kernel(const float* __restrict__ src, unsigned short* __restrict__ dst, int K) {
    __shared__ char lsm[16384];
    const int t   = threadIdx.x;       // 0..255
    const int nkc = K >> 8;            // K/256
    const int b   = blockIdx.x / nkc;  // 32-row band
    const int kc  = blockIdx.x % nkc;
    const int k0  = kc << 8;
    const int r   = t >> 3;            // 0..31 row within band
    const int j   = t & 7;             // 0..7  32-float group within 256-k slice

    const float4* s4 = (const float4*)(src + (size_t)((b << 5) + r) * K + k0 + (j << 5));
    float4 f[8];
#pragma unroll
    for (int i = 0; i < 8; ++i) f[i] = s4[i];

#pragma unroll
    for (int gi = 0; gi < 4; ++gi) {
        float4 lo = f[2 * gi], hi4 = f[2 * gi + 1];
        u16x8 o;
        if (DO_DEQUANT) {
            o[0] = f2bf(dequant(lo.x));  o[1] = f2bf(dequant(lo.y));
            o[2] = f2bf(dequant(lo.z));  o[3] = f2bf(dequant(lo.w));
            o[4] = f2bf(dequant(hi4.x)); o[5] = f2bf(dequant(hi4.y));
            o[6] = f2bf(dequant(hi4.z)); o[7] = f2bf(dequant(hi4.w));
        } else {
            o[0] = f2bf(lo.x);  o[1] = f2bf(lo.y);  o[2] = f2bf(lo.z);  o[3] = f2bf(lo.w);
            o[4] = f2bf(hi4.x); o[5] = f2bf(hi4.y); o[6] = f2bf(hi4.z); o[7] = f2bf(hi4.w);
        }
        const int S_rel = 2 * j + (gi >> 1);       // 0..15 chunk within block
        const int slot  = ((gi & 1) << 5) + r;     // hi*32 + r
        *(u16x8*)(lsm + S_rel * 1024 + slot * 16) = o;
    }
    __syncthreads();

    // block's 16 chunks are contiguous in packed space
    unsigned short* gdst = dst + (((size_t)b * (K >> 4) + (kc << 4)) << 9) + (size_t)t * 32;
#pragma unroll
    for (int i = 0; i < 4; ++i)
        *(u16x8*)(gdst + i * 8) = *(const u16x8*)(lsm + t * 64 + i * 16);
}

// ---------------------------------------------------------------------------
// 256x256 8-phase bf16 GEMM with 32x32x16 MFMA, chunk-linear packed inputs.
// C[M,N] = A[M,K] * B[N,K]^T + bias, fp32 out.
// 8 waves (2Mx4N), per-wave 128x64 = 4x2 frags of 32x32.
// LDS half-tile (16 KiB) = 16 chunks of 1KB, chunk (band, ks):
//   slot l holds row band*32+(l&31), k = 16*(S_half+ks) + (l>>5)*8 .. +7.
// Staging: global source is packed chunk-linear -> each global_load_lds is a
// fully-contiguous 1KB burst; LDS dest linear; fragment reads lane-linear
// (base + l*16): zero bank conflicts. BK=64 as two 32-k halves, double-
// buffered, counted vmcnt(8), raw s_barrier, setprio, XCD-swizzled blockIdx.
// ---------------------------------------------------------------------------

__device__ __forceinline__ bfrag_t rdfrag32(const char* halfBase, int band, int ks, int l16) {
    return *(const bfrag_t*)(halfBase + (band << 11) + (ks << 10) + l16);
}

__device__ __forceinline__ void mfma_half(f32x16 (&acc)[4][2], int mbase,
                                          const bfrag_t (&a)[2][2], const bfrag_t (&b)[2][2]) {
#pragma unroll
    for (int ks = 0; ks < 2; ++ks)
#pragma unroll
        for (int mi = 0; mi < 2; ++mi)
#pragma unroll
            for (int nn = 0; nn < 2; ++nn)
                acc[mbase + mi][nn] = __builtin_amdgcn_mfma_f32_32x32x16_bf16(
                    a[mi][ks], b[nn][ks], acc[mbase + mi][nn], 0, 0, 0);
}

__global__ __launch_bounds__(512, 2) void gemm256_kernel(
        const unsigned short* __restrict__ Ap,  // M x K, packed chunk-linear
        const unsigned short* __restrict__ Bp,  // N x K, packed chunk-linear
        const float* __restrict__ bias,         // N
        float* __restrict__ C,                  // M x N
        int M, int N, int K) {
    __shared__ unsigned short lds[65536];       // 128 KiB: 2 bufs x {A0,A1,B0,B1} x 16 KiB
    char* ldsB = (char*)lds;

    const int t    = threadIdx.x;
    const int w    = t >> 6;        // wave 0..7
    const int l    = t & 63;
    const int wr   = w >> 2;        // 0..1  (128-row band)
    const int wc   = w & 3;         // 0..3  (64-col band)
    const int lr32 = l & 31;
    const int hi   = l >> 5;
    const int l16  = l << 4;

    // XCD-aware block swizzle (bijective when nwg % 8 == 0)
    const int nwg = gridDim.x;
    int bid = blockIdx.x;
    if ((nwg & 7) == 0) bid = (bid & 7) * (nwg >> 3) + (bid >> 3);
    const int nbn  = N >> 8;
    const int brow = (bid / nbn) << 8;
    const int bcol = (bid % nbn) << 8;

    // packed staging bases: wave w stages band w of the tile; per-lane +l*16
    const int Kc = K >> 4;          // S-chunks per row-band
    const char* pA = (const char*)Ap + (((size_t)(((brow >> 5) + w) * (size_t)Kc)) << 10) + l16;
    const char* pB = (const char*)Bp + (((size_t)(((bcol >> 5) + w) * (size_t)Kc)) << 10) + l16;
    const int c16a = w * 2 + 0, c16b = w * 2 + 1;

    // LDS half-tile bases (bytes): buf*65536 + {A0:0, A1:16384, B0:32768, B1:49152}
#define STAGE_A(buf, half, kE)                                                              \
    do {                                                                                    \
        const size_t so_ = ((size_t)(((kE) >> 4) + (half) * 2)) << 10;                      \
        GLD16(pA + so_,        ldsB + (buf) * 65536 + (half) * 16384 + c16a * 1024);        \
        GLD16(pA + so_ + 1024, ldsB + (buf) * 65536 + (half) * 16384 + c16b * 1024);        \
    } while (0)
#define STAGE_B(buf, half, kE)                                                              \
    do {                                                                                    \
        const size_t so_ = ((size_t)(((kE) >> 4) + (half) * 2)) << 10;                      \
        GLD16(pB + so_,        ldsB + (buf) * 65536 + 32768 + (half) * 16384 + c16a * 1024);\
        GLD16(pB + so_ + 1024, ldsB + (buf) * 65536 + 32768 + (half) * 16384 + c16b * 1024);\
    } while (0)

    f32x16 acc[4][2];
#pragma unroll
    for (int m = 0; m < 4; ++m)
#pragma unroll
        for (int n = 0; n < 2; ++n)
#pragma unroll
            for (int r = 0; r < 16; ++r)
                acc[m][n][r] = 0.f;

    const int NT = K >> 6;
    const int wrB4 = wr << 2;       // A band base: wr*4 (+mi, +2+mi)
    const int wcB2 = wc << 1;       // B band base: wc*2 (+nn)
    const int wrBase = wr << 7;
    const int wcBase = wc << 6;

    // ---- prologue: buf0 fully (A0,B0,A1,B1), buf1 (A0,B0) ----
    {
        const int k1 = (NT > 1) ? 64 : 0;
        STAGE_A(0, 0, 0); STAGE_B(0, 0, 0);
        STAGE_A(0, 1, 0); STAGE_B(0, 1, 0);
        STAGE_A(1, 0, k1); STAGE_B(1, 0, k1);
        WAITVM(4);          // buf0 complete; buf1.A0/B0 (4 issues) stay in flight
        BAR();
    }

    for (int tt = 0; tt < NT; ++tt) {
        const int X = tt & 1, Y = X ^ 1;
        const char* aH0 = ldsB + X * 65536;
        const char* aH1 = aH0 + 16384;
        const char* bH0 = aH0 + 32768;
        const char* bH1 = aH0 + 49152;
        int t1 = tt + 1; if (t1 >= NT) t1 -= NT;   // wrapped: data harmless, never read
        int t2 = tt + 2; if (t2 >= NT) t2 -= NT;
        const int kY1 = t1 << 6;
        const int kX2 = t2 << 6;

        bfrag_t a[2][2], b[2][2];

        // ---- phase 1: A m0-1 + B all (k-half 0); stage Y.A1(t+1); 8 MFMA ----
#pragma unroll
        for (int mi = 0; mi < 2; ++mi)
#pragma unroll
            for (int ks = 0; ks < 2; ++ks)
                a[mi][ks] = rdfrag32(aH0, wrB4 + mi, ks, l16);
#pragma unroll
        for (int nn = 0; nn < 2; ++nn)
#pragma unroll
            for (int ks = 0; ks < 2; ++ks)
                b[nn][ks] = rdfrag32(bH0, wcB2 + nn, ks, l16);
        STAGE_A(Y, 1, kY1);
        BAR();
        __builtin_amdgcn_s_setprio(1);
        mfma_half(acc, 0, a, b);
        __builtin_amdgcn_s_setprio(0);
        BAR();

        // ---- phase 2: A m2-3 (k-half 0); stage Y.B1(t+1); 8 MFMA ----
#pragma unroll
        for (int mi = 0; mi < 2; ++mi)
#pragma unroll
            for (int ks = 0; ks < 2; ++ks)
                a[mi][ks] = rdfrag32(aH0, wrB4 + 2 + mi, ks, l16);
        STAGE_B(Y, 1, kY1);
        BAR();
        __builtin_amdgcn_s_setprio(1);
        mfma_half(acc, 2, a, b);
        __builtin_amdgcn_s_setprio(0);
        WAITVM(8);          // completes buf(t).A1/B1 for phase 3
        BAR();

        // ---- phase 3: A m0-1 + B all (k-half 1); stage X.A0(t+2); 8 MFMA ----
#pragma unroll
        for (int mi = 0; mi < 2; ++mi)
#pragma unroll
            for (int ks = 0; ks < 2; ++ks)
                a[mi][ks] = rdfrag32(aH1, wrB4 + mi, ks, l16);
#pragma unroll
        for (int nn = 0; nn < 2; ++nn)
#pragma unroll
            for (int ks = 0; ks < 2; ++ks)
                b[nn][ks] = rdfrag32(bH1, wcB2 + nn, ks, l16);
        STAGE_A(X, 0, kX2);                      // X.A0 free: last read was phase 2
        BAR();
        __builtin_amdgcn_s_setprio(1);
        mfma_half(acc, 0, a, b);
        __builtin_amdgcn_s_setprio(0);
        BAR();

        // ---- phase 4: A m2-3 (k-half 1); stage X.B0(t+2); 8 MFMA ----
#pragma unroll
        for (int mi = 0; mi < 2; ++mi)
#pragma unroll
            for (int ks = 0; ks < 2; ++ks)
                a[mi][ks] = rdfrag32(aH1, wrB4 + 2 + mi, ks, l16);
        STAGE_B(X, 0, kX2);                      // X.B0 free: last read was phase 1
        BAR();
        __builtin_amdgcn_s_setprio(1);
        mfma_half(acc, 2, a, b);
        __builtin_amdgcn_s_setprio(0);
        WAITVM(8);          // completes buf(t+1).A0/B0 for next tile's phase 1
        BAR();
    }

    WAITVM(0);              // drain pending LDS writes before wave retires

    // ---- epilogue: 32x32 C/D layout col=lane&31, row=(reg&3)+8*(reg>>2)+4*(lane>>5) ----
    float bv[2];
#pragma unroll
    for (int nn = 0; nn < 2; ++nn) bv[nn] = bias[bcol + wcBase + nn * 32 + lr32];
#pragma unroll
    for (int mm = 0; mm < 4; ++mm) {
#pragma unroll
        for (int nn = 0; nn < 2; ++nn) {
            const int gc = bcol + wcBase + nn * 32 + lr32;
#pragma unroll
            for (int reg = 0; reg < 16; ++reg) {
                const int row = (reg & 3) + 8 * (reg >> 2) + 4 * hi;
                C[(size_t)(brow + wrBase + mm * 32 + row) * N + gc] = acc[mm][nn][reg] + bv[nn];
            }
        }
    }
    (void)M;
#undef STAGE_A
#undef STAGE_B
}

// ---------------------------------------------------------------------------
// Fallback: fp32 tiled GEMM with on-the-fly dequant (any shape, slow).
// ---------------------------------------------------------------------------
__global__ void gemm_fallback_kernel(const float* __restrict__ X, const float* __restrict__ W,
                                     const float* __restrict__ bias, float* __restrict__ C,
                                     int M, int N, int K) {
    __shared__ float sX[16][17];
    __shared__ float sW[16][17];
    const int tx = threadIdx.x & 15;
    const int ty = threadIdx.x >> 4;
    const int row = blockIdx.y * 16 + ty;
    const int colBase = blockIdx.x * 16;
    const int col = colBase + tx;
    float acc = 0.f;
    for (int k0 = 0; k0 < K; k0 += 16) {
        sX[ty][tx] = (row < M && k0 + tx < K) ? X[(size_t)row * K + k0 + tx] : 0.f;
        const int wrow = colBase + ty;
        sW[ty][tx] = (wrow < N && k0 + tx < K) ? dequant(W[(size_t)wrow * K + k0 + tx]) : 0.f;
        __syncthreads();
#pragma unroll
        for (int kk = 0; kk < 16; ++kk)
            acc += sX[ty][kk] * sW[tx][kk];
        __syncthreads();
    }
    if (row < M && col < N)
        C[(size_t)row * N + col] = acc + bias[col];
}

extern "C" void kernel_launch(void* const* d_in, const int* in_sizes, int n_in,
                              void* d_out, int out_size, void* d_ws, size_t ws_size,
                              hipStream_t stream) {
    const float* x    = (const float*)d_in[0];
    const float* w    = (const float*)d_in[1];
    const float* bias = (const float*)d_in[2];
    float* out        = (float*)d_out;

    const int N = in_sizes[2];
    const int K = in_sizes[1] / N;
    const int M = in_sizes[0] / K;

    const size_t need = ((size_t)M * K + (size_t)N * K) * sizeof(unsigned short);
    const bool fast = (ws_size >= need) && (M % 256 == 0) && (N % 256 == 0) &&
                      (K % 256 == 0);

    if (fast) {
        unsigned short* xp = (unsigned short*)d_ws;
        unsigned short* wp = xp + (size_t)M * K;
        pack_kernel<false><<<dim3((M / 32) * (K / 256)), dim3(256), 0, stream>>>(x, xp, K);
        pack_kernel<true ><<<dim3((N / 32) * (K / 256)), dim3(256), 0, stream>>>(w, wp, K);
        gemm256_kernel<<<dim3((M / 256) * (N / 256)), dim3(512), 0, stream>>>(xp, wp, bias, out, M, N, K);
    } else {
        dim3 g((N + 15) / 16, (M + 15) / 16);
        gemm_fallback_kernel<<<g, dim3(256), 0, stream>>>(x, w, bias, out, M, N, K);
    }
    (void)n_in; (void)out_size;
}